// Round 1
// baseline (832.418 us; speedup 1.0000x reference)
//
#include <hip/hip_runtime.h>
#include <math.h>

// ---------------------------------------------------------------------------
// Sizes (fixed by the problem)
#define B_ROWS   8192
#define NZ       100
#define NC       2
#define H1       256
#define H2       64
#define FEATN    8192
#define FDIM     1024
#define RROWS    16      // rows per workgroup in k_main

// ---------------------------------------------------------------------------
// JAX threefry2x32, partitionable variant, key = (0, 42), counter = (0, i)
__device__ __forceinline__ unsigned rotl32(unsigned v, int r) {
    return (v << r) | (v >> (32 - r));
}

__device__ __forceinline__ unsigned threefry_bits(unsigned lo) {
    const unsigned ks0 = 0u;
    const unsigned ks1 = 42u;
    const unsigned ks2 = 0x1BD11BDAu ^ 42u;
    unsigned x0 = 0u + ks0;     // hi counter = 0 (flat index < 2^26)
    unsigned x1 = lo + ks1;
#define TF_R4(a,b,c,d) \
    x0 += x1; x1 = rotl32(x1,a); x1 ^= x0; \
    x0 += x1; x1 = rotl32(x1,b); x1 ^= x0; \
    x0 += x1; x1 = rotl32(x1,c); x1 ^= x0; \
    x0 += x1; x1 = rotl32(x1,d); x1 ^= x0;
    TF_R4(13,15,26,6);  x0 += ks1; x1 += ks2 + 1u;
    TF_R4(17,29,16,24); x0 += ks2; x1 += ks0 + 2u;
    TF_R4(13,15,26,6);  x0 += ks0; x1 += ks1 + 3u;
    TF_R4(17,29,16,24); x0 += ks1; x1 += ks2 + 4u;
    TF_R4(13,15,26,6);  x0 += ks2; x1 += ks0 + 5u;
#undef TF_R4
    return x0 ^ x1;   // 32-bit partitionable output folds the two halves
}

// Gumbel noise exactly as the reference: U = 0.001*u; g = -log(-log(U+1e-3)+1e-3)
__device__ __forceinline__ float gumbel_g(unsigned flat) {
    unsigned bits = threefry_bits(flat);
    float u  = __uint_as_float((bits >> 9) | 0x3f800000u) - 1.0f;
    float U  = 0.001f * u;          // fp32, as in reference
    float t1 = U + 0.001f;          // fp32
    float L1 = (float)log((double)t1);   // fp64 log, rounded to fp32
    float A  = 0.001f - L1;         // fp32 (= -L1 + eps)
    float L2 = (float)log((double)A);
    return -L2;
}

// ---------------------------------------------------------------------------
// K1: a1[b,j] = z[b,:] @ W1[:,j] + b1[j]   (z = concat(x,y)), fp64 accumulate
__global__ __launch_bounds__(256) void k_a1(
    const float* __restrict__ x, const float* __restrict__ y,
    const float* __restrict__ W1, const float* __restrict__ b1,
    float* __restrict__ a1)
{
    const int j  = threadIdx.x;          // feature 0..255
    const int b0 = blockIdx.x * 8;       // 8 rows per block
    double acc[8];
#pragma unroll
    for (int r = 0; r < 8; ++r) acc[r] = 0.0;

    for (int i = 0; i < NZ; ++i) {
        float w = W1[i * H1 + j];        // coalesced across j
#pragma unroll
        for (int r = 0; r < 8; ++r)
            acc[r] += (double)x[(b0 + r) * NZ + i] * (double)w;  // scalar bcast
    }
#pragma unroll
    for (int i = 0; i < NC; ++i) {
        float w = W1[(NZ + i) * H1 + j];
#pragma unroll
        for (int r = 0; r < 8; ++r)
            acc[r] += (double)y[(b0 + r) * NC + i] * (double)w;
    }
    double bb = (double)b1[j];
#pragma unroll
    for (int r = 0; r < 8; ++r)
        a1[(b0 + r) * H1 + j] = (float)(acc[r] + bb);
}

// ---------------------------------------------------------------------------
// BN stats: one block per feature column; biased variance; fold gamma/beta:
//   h = a*scale + shift  with scale = gamma*rstd, shift = beta - mean*scale
__global__ __launch_bounds__(1024) void k_stats(
    const float* __restrict__ A, int ncol,
    const float* __restrict__ gamma, const float* __restrict__ beta,
    float* __restrict__ scale, float* __restrict__ shift)
{
    const int j = blockIdx.x;
    const int t = threadIdx.x;
    double s = 0.0, s2 = 0.0;
    for (int r = t; r < B_ROWS; r += 1024) {
        double v = (double)A[r * ncol + j];
        s += v; s2 += v * v;
    }
    __shared__ double ls[1024];
    __shared__ double ls2[1024];
    ls[t] = s; ls2[t] = s2;
    __syncthreads();
    for (int k = 512; k > 0; k >>= 1) {
        if (t < k) { ls[t] += ls[t + k]; ls2[t] += ls2[t + k]; }
        __syncthreads();
    }
    if (t == 0) {
        double mean = ls[0] * (1.0 / B_ROWS);
        double var  = ls2[0] * (1.0 / B_ROWS) - mean * mean;
        double rstd = 1.0 / sqrt(var + 1e-5);
        double sc   = (double)gamma[j] * rstd;
        scale[j] = (float)sc;
        shift[j] = (float)((double)beta[j] - mean * sc);
    }
}

// ---------------------------------------------------------------------------
// K3: a2[b,k] = relu(bn(a1[b,:])) @ W2[:,k] + b2[k], fp64 accumulate
__global__ __launch_bounds__(256) void k_a2(
    const float* __restrict__ a1,
    const float* __restrict__ sc1, const float* __restrict__ sh1,
    const float* __restrict__ W2, const float* __restrict__ b2,
    float* __restrict__ a2)
{
    const int t  = threadIdx.x;
    const int k  = t & 63;               // output feature 0..63
    const int rr = t >> 6;               // row-within-block 0..3 (one wave each)
    const int b  = blockIdx.x * 4 + rr;
    double acc = 0.0;
    for (int j = 0; j < H1; ++j) {
        float h = fmaxf(fmaf(a1[b * H1 + j], sc1[j], sh1[j]), 0.0f); // uniform per wave
        acc += (double)h * (double)W2[j * H2 + k];                   // coalesced
    }
    a2[b * H2 + k] = (float)(acc + (double)b2[k]);
}

// ---------------------------------------------------------------------------
// K5: per 16-row block: logits rowmax pass, then noise-pruned candidate pass,
//     argmax over (logit + gumbel), gather codebook row -> out.
__global__ __launch_bounds__(256) void k_main(
    const float* __restrict__ a2,
    const float* __restrict__ sc2, const float* __restrict__ sh2,
    const float* __restrict__ W3, const float* __restrict__ b3,
    const float* __restrict__ codebook, float* __restrict__ out)
{
    const int t  = threadIdx.x;
    const int b0 = blockIdx.x * RROWS;

    __shared__ float h2T[64][RROWS];        // [j][r], broadcast reads
    __shared__ float redf[RROWS][257];      // +1 pad vs bank conflicts
    __shared__ int   redi[RROWS][257];
    __shared__ float rowThresh[RROWS];
    __shared__ int   rowInd[RROWS];

    // h2 = relu(bn(a2)) for our 16 rows, into LDS (j-major for b128 reads)
    for (int q = t; q < RROWS * 64; q += 256) {
        int r = q >> 6, j = q & 63;
        float v = a2[(b0 + r) * H2 + j];
        h2T[j][r] = fmaxf(fmaf(v, sc2[j], sh2[j]), 0.0f);
    }
    __syncthreads();

    // ---- Pass A: rowmax of logits (no noise) ----
    float rmaxL[RROWS];
#pragma unroll
    for (int r = 0; r < RROWS; ++r) rmaxL[r] = -1e30f;

    for (int fc = 0; fc < FEATN / 256; ++fc) {
        const int f = (fc << 8) + t;
        float acc[RROWS];
        float bb = b3[f];
#pragma unroll
        for (int r = 0; r < RROWS; ++r) acc[r] = bb;
#pragma unroll 4
        for (int j = 0; j < 64; ++j) {
            float w = W3[j * FEATN + f];           // coalesced, L2-resident
#pragma unroll
            for (int r = 0; r < RROWS; ++r)
                acc[r] = fmaf(h2T[j][r], w, acc[r]);
        }
#pragma unroll
        for (int r = 0; r < RROWS; ++r) rmaxL[r] = fmaxf(rmaxL[r], acc[r]);
    }
#pragma unroll
    for (int r = 0; r < RROWS; ++r) redf[r][t] = rmaxL[r];
    __syncthreads();
    if (t < RROWS) {
        float m = -1e30f;
        for (int i = 0; i < 256; ++i) m = fmaxf(m, redf[t][i]);
        // gumbel range is 0.10581; margin covers it + logit error slack
        rowThresh[t] = m - 0.1068f;
    }
    __syncthreads();
    float thr[RROWS];
#pragma unroll
    for (int r = 0; r < RROWS; ++r) thr[r] = rowThresh[r];

    // ---- Pass B: recompute logits (bit-identical), score candidates ----
    float bestS[RROWS];
    int   bestI[RROWS];
#pragma unroll
    for (int r = 0; r < RROWS; ++r) { bestS[r] = -1e30f; bestI[r] = 0x7fffffff; }

    for (int fc = 0; fc < FEATN / 256; ++fc) {
        const int f = (fc << 8) + t;
        float acc[RROWS];
        float bb = b3[f];
#pragma unroll
        for (int r = 0; r < RROWS; ++r) acc[r] = bb;
#pragma unroll 4
        for (int j = 0; j < 64; ++j) {
            float w = W3[j * FEATN + f];
#pragma unroll
            for (int r = 0; r < RROWS; ++r)
                acc[r] = fmaf(h2T[j][r], w, acc[r]);
        }
#pragma unroll
        for (int r = 0; r < RROWS; ++r) {
            if (acc[r] >= thr[r]) {                 // ~2-4 candidates per row
                unsigned flat = (unsigned)(b0 + r) * (unsigned)FEATN + (unsigned)f;
                float sc = acc[r] + gumbel_g(flat);
                if (sc > bestS[r] || (sc == bestS[r] && f < bestI[r])) {
                    bestS[r] = sc; bestI[r] = f;
                }
            }
        }
    }
#pragma unroll
    for (int r = 0; r < RROWS; ++r) { redf[r][t] = bestS[r]; redi[r][t] = bestI[r]; }
    __syncthreads();
    if (t < RROWS) {
        float bs = -1e30f; int bi = 0x7fffffff;
        for (int i = 0; i < 256; ++i) {
            float s = redf[t][i]; int ix = redi[t][i];
            if (s > bs || (s == bs && ix < bi)) { bs = s; bi = ix; }
        }
        rowInd[t] = bi;
    }
    __syncthreads();

    // ---- Output: out[b,:] = codebook[ind,:]  (z_st scale == 1 to 1e-7) ----
    for (int r = 0; r < RROWS; ++r) {
        int ind = rowInd[r];
        const float4* src = (const float4*)(codebook + (size_t)ind * FDIM);
        float4*       dst = (float4*)(out + (size_t)(b0 + r) * FDIM);
        dst[t] = src[t];   // 256 threads x 16B = 4 KB row
    }
}

// ---------------------------------------------------------------------------
extern "C" void kernel_launch(void* const* d_in, const int* in_sizes, int n_in,
                              void* d_out, int out_size, void* d_ws, size_t ws_size,
                              hipStream_t stream)
{
    const float* x   = (const float*)d_in[0];
    const float* y   = (const float*)d_in[1];
    const float* W1  = (const float*)d_in[2];
    const float* b1  = (const float*)d_in[3];
    const float* g1  = (const float*)d_in[4];
    const float* be1 = (const float*)d_in[5];
    const float* W2  = (const float*)d_in[6];
    const float* b2  = (const float*)d_in[7];
    const float* g2  = (const float*)d_in[8];
    const float* be2 = (const float*)d_in[9];
    const float* W3  = (const float*)d_in[10];
    const float* b3  = (const float*)d_in[11];
    const float* cb  = (const float*)d_in[12];
    float* out = (float*)d_out;

    float* ws  = (float*)d_ws;
    float* a1  = ws;                        // 8192*256
    float* a2  = a1 + B_ROWS * H1;          // 8192*64
    float* sc1 = a2 + B_ROWS * H2;          // 256
    float* sh1 = sc1 + H1;                  // 256
    float* sc2 = sh1 + H1;                  // 64
    float* sh2 = sc2 + H2;                  // 64
    // total ~10.5 MB of ws

    k_a1   <<<B_ROWS / 8, 256, 0, stream>>>(x, y, W1, b1, a1);
    k_stats<<<H1, 1024, 0, stream>>>(a1, H1, g1, be1, sc1, sh1);
    k_a2   <<<B_ROWS / 4, 256, 0, stream>>>(a1, sc1, sh1, W2, b2, a2);
    k_stats<<<H2, 1024, 0, stream>>>(a2, H2, g2, be2, sc2, sh2);
    k_main <<<B_ROWS / RROWS, 256, 0, stream>>>(a2, sc2, sh2, W3, b3, cb, out);
}